// Round 2
// baseline (89.829 us; speedup 1.0000x reference)
//
#include <hip/hip_runtime.h>

#define NBINS 51
#define NT    32          // tiles per dimension (1024 / 32)
#define TILE  32          // rows per tile
#define DV4   32          // 128 floats = 32 float4 per row
#define NBLK  (NT * (NT + 1) / 2)   // 528
#define NCOPY 16
#define HSTR  103         // hist copy stride (odd -> banks decorrelated)

// ---------------------------------------------------------------------------
// Kernel 1: pairwise dots (upper triangle) + soft histogram.
// 528 blocks x 256 threads, 2x2 micro-tile per thread.
// 16 privatized LDS histograms (copy = t&15) -> max 4-way same-address
// collision per wave atomic. Per-block result written (no global atomics)
// to partial[bin][block] (transposed for coalesced reduction in kernel 2).
// ---------------------------------------------------------------------------
__global__ __launch_bounds__(256) void pair_hist_kernel(
    const float* __restrict__ x,
    const int*   __restrict__ labels,
    float*       __restrict__ partial)   // [2*NBINS][NBLK]
{
    __shared__ float4 As[TILE][DV4];   // chunk c stored at c ^ ((row>>1)&7)
    __shared__ float4 Bs[TILE][DV4];
    __shared__ int    la[TILE], lb[TILE];
    __shared__ float  shist[NCOPY * HSTR];

    // Decode upper-triangular tile pair (bi <= bj).
    int rem = blockIdx.x;
    int bi = 0;
    while (rem >= NT - bi) { rem -= NT - bi; ++bi; }
    const int bj = bi + rem;

    const int t = threadIdx.x;
    for (int k = t; k < NCOPY * HSTR; k += 256) shist[k] = 0.0f;

    const float4* xv = (const float4*)x;
    #pragma unroll
    for (int k = 0; k < 4; ++k) {
        int e = t + 256 * k;
        int r = e >> 5;
        int c = e & 31;
        int sw = c ^ ((r >> 1) & 7);
        As[r][sw] = xv[(bi * TILE + r) * DV4 + c];
        Bs[r][sw] = xv[(bj * TILE + r) * DV4 + c];
    }
    if (t < TILE) {
        la[t] = labels[bi * TILE + t];
        lb[t] = labels[bj * TILE + t];
    }
    __syncthreads();

    const int tx = t & 15;
    const int ty = t >> 4;
    const int i0 = ty * 2, j0 = tx * 2;
    const int kA = ty & 7;
    const int kB = tx & 7;

    float acc00 = 0.f, acc01 = 0.f, acc10 = 0.f, acc11 = 0.f;
    #pragma unroll 4
    for (int d4 = 0; d4 < DV4; ++d4) {
        float4 a0 = As[i0    ][d4 ^ kA];
        float4 a1 = As[i0 + 1][d4 ^ kA];
        float4 b0 = Bs[j0    ][d4 ^ kB];
        float4 b1 = Bs[j0 + 1][d4 ^ kB];
        acc00 += a0.x*b0.x + a0.y*b0.y + a0.z*b0.z + a0.w*b0.w;
        acc01 += a0.x*b1.x + a0.y*b1.y + a0.z*b1.z + a0.w*b1.w;
        acc10 += a1.x*b0.x + a1.y*b0.y + a1.z*b0.z + a1.w*b0.w;
        acc11 += a1.x*b1.x + a1.y*b1.y + a1.z*b1.z + a1.w*b1.w;
    }

    const float BW = 2.0f / (NBINS - 1);
    float accs[2][2] = {{acc00, acc01}, {acc10, acc11}};
    float* myh = &shist[(t & (NCOPY - 1)) * HSTR];

    #pragma unroll
    for (int r = 0; r < 2; ++r) {
        #pragma unroll
        for (int c = 0; c < 2; ++c) {
            int gi = bi * TILE + i0 + r;
            int gj = bj * TILE + j0 + c;
            if (gi < gj) {
                float s = accs[r][c];
                int b = (int)floorf((s + 1.0f) / BW);
                b = min(max(b, 0), NBINS - 1);
                float v = (float)b * BW - 1.0f;
                float wlo = (v + BW - s) / BW;
                float whi = (s - v) / BW;
                int bh = min(b + 1, NBINS - 1);
                int base = (la[i0 + r] == lb[j0 + c]) ? 0 : NBINS;
                atomicAdd(&myh[base + b],  wlo);
                atomicAdd(&myh[base + bh], whi);
            }
        }
    }

    __syncthreads();
    // Reduce 16 copies; one coalesced store per bin (no global atomics).
    if (t < 2 * NBINS) {
        float s = 0.f;
        #pragma unroll
        for (int c = 0; c < NCOPY; ++c) s += shist[c * HSTR + t];
        partial[t * NBLK + blockIdx.x] = s;
    }
}

// ---------------------------------------------------------------------------
// Kernel 2: reduce 528 partials per bin, then CDF + loss (wave 0).
// ---------------------------------------------------------------------------
__global__ __launch_bounds__(1024) void finalize_kernel(
    const float* __restrict__ partial,
    float*       __restrict__ out)
{
    __shared__ float h[2 * NBINS];
    const int t = threadIdx.x;
    const int wave = t >> 6, lane = t & 63;

    for (int bin = wave; bin < 2 * NBINS; bin += 16) {
        float s = 0.f;
        for (int idx = lane; idx < NBLK; idx += 64)
            s += partial[bin * NBLK + idx];
        #pragma unroll
        for (int off = 32; off > 0; off >>= 1)
            s += __shfl_xor(s, off, 64);
        if (lane == 0) h[bin] = s;
    }
    __syncthreads();

    if (t < 64) {
        float hp = (t < NBINS) ? h[t]         : 0.0f;
        float hn = (t < NBINS) ? h[NBINS + t] : 0.0f;

        float sp = hp, sn = hn;
        #pragma unroll
        for (int off = 32; off > 0; off >>= 1) {
            sp += __shfl_xor(sp, off, 64);
            sn += __shfl_xor(sn, off, 64);
        }

        float cdf = hp;
        #pragma unroll
        for (int off = 1; off < 64; off <<= 1) {
            float v = __shfl_up(cdf, off, 64);
            if (t >= off) cdf += v;
        }

        float contrib = hn * cdf;
        #pragma unroll
        for (int off = 32; off > 0; off >>= 1)
            contrib += __shfl_xor(contrib, off, 64);

        if (t == 0) out[0] = contrib / (sp * sn);
    }
}

extern "C" void kernel_launch(void* const* d_in, const int* in_sizes, int n_in,
                              void* d_out, int out_size, void* d_ws, size_t ws_size,
                              hipStream_t stream)
{
    const float* x       = (const float*)d_in[0];
    const int*   labels  = (const int*)d_in[1];
    float*       partial = (float*)d_ws;   // [2*NBINS][NBLK], fully written

    pair_hist_kernel<<<NBLK, 256, 0, stream>>>(x, labels, partial);
    finalize_kernel<<<1, 1024, 0, stream>>>(partial, (float*)d_out);
}

// Round 3
// 78.897 us; speedup vs baseline: 1.1386x; 1.1386x over previous
//
#include <hip/hip_runtime.h>

#define NBINS 51
#define NT    32          // tiles per dimension (1024 / 32)
#define TILE  32          // rows per tile
#define DV4   32          // 128 floats = 32 float4 per row
#define NBLK  (NT * (NT + 1) / 2)   // 528
#define NCOPY 16
#define HSTR  103         // hist copy stride (odd -> banks decorrelated)

// ---------------------------------------------------------------------------
// Kernel 1: pairwise dots (upper triangle) + soft histogram.
// 528 blocks x 256 threads, 2x2 micro-tile per thread.
// All fp32 atomics are unsafeAtomicAdd -> native ds_add_f32 /
// global_atomic_add_f32 (fire-and-forget). Default atomicAdd(float*) is a
// CAS retry loop on gfx950 and serialized catastrophically under the
// same-address contention here (hot bins near s=0). ghist: [0..50]=pos,
// [51..101]=neg, unnormalized.
// ---------------------------------------------------------------------------
__global__ __launch_bounds__(256) void pair_hist_kernel(
    const float* __restrict__ x,
    const int*   __restrict__ labels,
    float*       __restrict__ ghist)
{
    __shared__ float4 As[TILE][DV4];   // chunk c stored at c ^ ((row>>1)&7)
    __shared__ float4 Bs[TILE][DV4];
    __shared__ int    la[TILE], lb[TILE];
    __shared__ float  shist[NCOPY * HSTR];

    // Decode upper-triangular tile pair (bi <= bj).
    int rem = blockIdx.x;
    int bi = 0;
    while (rem >= NT - bi) { rem -= NT - bi; ++bi; }
    const int bj = bi + rem;

    const int t = threadIdx.x;
    for (int k = t; k < NCOPY * HSTR; k += 256) shist[k] = 0.0f;

    const float4* xv = (const float4*)x;
    #pragma unroll
    for (int k = 0; k < 4; ++k) {
        int e = t + 256 * k;
        int r = e >> 5;
        int c = e & 31;
        int sw = c ^ ((r >> 1) & 7);
        As[r][sw] = xv[(bi * TILE + r) * DV4 + c];
        Bs[r][sw] = xv[(bj * TILE + r) * DV4 + c];
    }
    if (t < TILE) {
        la[t] = labels[bi * TILE + t];
        lb[t] = labels[bj * TILE + t];
    }
    __syncthreads();

    const int tx = t & 15;
    const int ty = t >> 4;
    const int i0 = ty * 2, j0 = tx * 2;
    const int kA = ty & 7;
    const int kB = tx & 7;

    float acc00 = 0.f, acc01 = 0.f, acc10 = 0.f, acc11 = 0.f;
    #pragma unroll 4
    for (int d4 = 0; d4 < DV4; ++d4) {
        float4 a0 = As[i0    ][d4 ^ kA];
        float4 a1 = As[i0 + 1][d4 ^ kA];
        float4 b0 = Bs[j0    ][d4 ^ kB];
        float4 b1 = Bs[j0 + 1][d4 ^ kB];
        acc00 += a0.x*b0.x + a0.y*b0.y + a0.z*b0.z + a0.w*b0.w;
        acc01 += a0.x*b1.x + a0.y*b1.y + a0.z*b1.z + a0.w*b1.w;
        acc10 += a1.x*b0.x + a1.y*b0.y + a1.z*b0.z + a1.w*b0.w;
        acc11 += a1.x*b1.x + a1.y*b1.y + a1.z*b1.z + a1.w*b1.w;
    }

    const float BW = 2.0f / (NBINS - 1);
    float accs[2][2] = {{acc00, acc01}, {acc10, acc11}};
    float* myh = &shist[(t & (NCOPY - 1)) * HSTR];

    #pragma unroll
    for (int r = 0; r < 2; ++r) {
        #pragma unroll
        for (int c = 0; c < 2; ++c) {
            int gi = bi * TILE + i0 + r;
            int gj = bj * TILE + j0 + c;
            if (gi < gj) {
                float s = accs[r][c];
                int b = (int)floorf((s + 1.0f) / BW);
                b = min(max(b, 0), NBINS - 1);
                float v = (float)b * BW - 1.0f;
                float wlo = (v + BW - s) / BW;
                float whi = (s - v) / BW;
                int bh = min(b + 1, NBINS - 1);
                int base = (la[i0 + r] == lb[j0 + c]) ? 0 : NBINS;
                unsafeAtomicAdd(&myh[base + b],  wlo);   // native ds_add_f32
                unsafeAtomicAdd(&myh[base + bh], whi);
            }
        }
    }

    __syncthreads();
    // Reduce 16 copies; one native global atomic per bin.
    if (t < 2 * NBINS) {
        float s = 0.f;
        #pragma unroll
        for (int c = 0; c < NCOPY; ++c) s += shist[c * HSTR + t];
        unsafeAtomicAdd(&ghist[t], s);                   // native global_atomic_add_f32
    }
}

// ---------------------------------------------------------------------------
// Kernel 2: one wave. Sums, CDF of pos hist (inclusive scan), loss.
// sum(hist) over bins == pair count (w_lo + w_hi == 1 per pair), so the
// normalizers come for free.
// ---------------------------------------------------------------------------
__global__ void finalize_kernel(const float* __restrict__ gh,
                                float* __restrict__ out)
{
    int t = threadIdx.x;   // 64 threads
    float hp = (t < NBINS) ? gh[t]         : 0.0f;
    float hn = (t < NBINS) ? gh[NBINS + t] : 0.0f;

    float sp = hp, sn = hn;
    #pragma unroll
    for (int off = 32; off > 0; off >>= 1) {
        sp += __shfl_xor(sp, off, 64);
        sn += __shfl_xor(sn, off, 64);
    }

    float cdf = hp;
    #pragma unroll
    for (int off = 1; off < 64; off <<= 1) {
        float v = __shfl_up(cdf, off, 64);
        if (t >= off) cdf += v;
    }

    float contrib = hn * cdf;
    #pragma unroll
    for (int off = 32; off > 0; off >>= 1)
        contrib += __shfl_xor(contrib, off, 64);

    if (t == 0) out[0] = contrib / (sp * sn);
}

extern "C" void kernel_launch(void* const* d_in, const int* in_sizes, int n_in,
                              void* d_out, int out_size, void* d_ws, size_t ws_size,
                              hipStream_t stream)
{
    const float* x      = (const float*)d_in[0];
    const int*   labels = (const int*)d_in[1];
    float*       ghist  = (float*)d_ws;

    hipMemsetAsync(ghist, 0, 2 * NBINS * sizeof(float), stream);
    pair_hist_kernel<<<NBLK, 256, 0, stream>>>(x, labels, ghist);
    finalize_kernel<<<1, 64, 0, stream>>>(ghist, (float*)d_out);
}